// Round 1
// baseline (119.038 us; speedup 1.0000x reference)
//
#include <hip/hip_runtime.h>

#define B_ 16
#define NPTS 4096            // points per batch (N == M == 4096)

constexpr int JT    = 1024;  // target-tile size (LDS: 16 KB of float4)
constexpr int PPT   = 4;     // query points per thread (registers)
constexpr int BLK   = 256;   // threads per block
constexpr int CHUNK = BLK * PPT;         // 1024 query points per block
constexpr int NCHUNK = NPTS / CHUNK;     // 4
constexpr int NJT    = NPTS / JT;        // 4

// ------------------------------------------------------------------
// prep: build target float4 {x,y,z,|t|^2} for both directions, and
// initialize the min-squared-distance arrays to +inf.
// i in [0, 2*B*NPTS): dir0 targets = gt, dir1 targets = pred.
__global__ void prep_kernel(const float* __restrict__ pred,
                            const float* __restrict__ gt,
                            float4* __restrict__ tgt4,
                            unsigned* __restrict__ minsq) {
    int i = blockIdx.x * blockDim.x + threadIdx.x;
    const int half = B_ * NPTS;
    const float* src = (i < half) ? gt : pred;
    int j = (i < half) ? i : i - half;
    float x = src[j * 3 + 0];
    float y = src[j * 3 + 1];
    float z = src[j * 3 + 2];
    tgt4[i] = make_float4(x, y, z, fmaf(x, x, fmaf(y, y, z * z)));
    minsq[i] = 0x7F800000u;   // +inf bits
}

// ------------------------------------------------------------------
// main pass: for each (dir, batch, query-chunk, target-tile) block,
// compute per-query min over the tile of (|g|^2 - 2 q.g), then fold in
// |q|^2, clamp >= 0, and atomicMin (uint order == float order for >=0).
__global__ __launch_bounds__(BLK) void chamfer_pass(
        const float* __restrict__ pred, const float* __restrict__ gt,
        const float4* __restrict__ tgt4, unsigned* __restrict__ minsq) {
    const int cx  = blockIdx.x & (NCHUNK - 1);   // query chunk
    const int jt  = blockIdx.x >> 2;             // target tile
    const int b   = blockIdx.y;
    const int dir = blockIdx.z;

    const float*  qsrc = dir ? gt : pred;        // queries
    const float4* tg   = tgt4  + dir * (B_ * NPTS) + b * NPTS + jt * JT;
    unsigned*     ms   = minsq + dir * (B_ * NPTS) + b * NPTS + cx * CHUNK;

    __shared__ float4 sh[JT];
    for (int k = threadIdx.x; k < JT; k += BLK)
        sh[k] = tg[k];

    float px[PPT], py[PPT], pz[PPT], mn[PPT];
    const int qbase = b * NPTS + cx * CHUNK + threadIdx.x;
#pragma unroll
    for (int q = 0; q < PPT; q++) {
        int idx = qbase + q * BLK;
        px[q] = qsrc[idx * 3 + 0];
        py[q] = qsrc[idx * 3 + 1];
        pz[q] = qsrc[idx * 3 + 2];
        mn[q] = 1e30f;
    }
    __syncthreads();

#pragma unroll 4
    for (int j = 0; j < JT; j++) {
        float4 g = sh[j];   // uniform address -> broadcast ds_read_b128
#pragma unroll
        for (int q = 0; q < PPT; q++) {
            float dot = fmaf(g.z, pz[q], fmaf(g.y, py[q], g.x * px[q]));
            float t   = fmaf(-2.0f, dot, g.w);
            mn[q] = fminf(mn[q], t);
        }
    }

#pragma unroll
    for (int q = 0; q < PPT; q++) {
        float x2 = fmaf(px[q], px[q], fmaf(py[q], py[q], pz[q] * pz[q]));
        float v  = fmaxf(mn[q] + x2, 0.0f);
        atomicMin(&ms[q * BLK + threadIdx.x], __float_as_uint(v));
    }
}

// ------------------------------------------------------------------
// reduce1: one block per (dir,b) slot; sum sqrt(minsq) over 4096 points.
__global__ void reduce1_kernel(const unsigned* __restrict__ minsq,
                               float* __restrict__ sums) {
    const unsigned* p = minsq + blockIdx.x * NPTS;
    float s = 0.0f;
    for (int k = threadIdx.x; k < NPTS; k += 256)
        s += sqrtf(__uint_as_float(p[k]));
    for (int off = 32; off; off >>= 1) s += __shfl_down(s, off);
    __shared__ float partial[4];
    if ((threadIdx.x & 63) == 0) partial[threadIdx.x >> 6] = s;
    __syncthreads();
    if (threadIdx.x == 0)
        sums[blockIdx.x] = partial[0] + partial[1] + partial[2] + partial[3];
}

// ------------------------------------------------------------------
// reduce2: combine 32 partial sums -> loss; write the 3 outputs.
__global__ void reduce2_kernel(const float* __restrict__ sums,
                               float* __restrict__ out) {
    float s = (threadIdx.x < 32) ? sums[threadIdx.x] : 0.0f;
    for (int off = 32; off; off >>= 1) s += __shfl_down(s, off);
    if (threadIdx.x == 0) {
        // loss = mean_b(mean_N(min) + mean_M(min)) = total / (B * 4096)
        float loss = s * (1.0f / (float)(B_ * NPTS));
        out[0] = loss;          // WEIGHT * loss, WEIGHT = 1
        out[1] = loss;          // helper_loss
        out[2] = 0.1f * loss;   // helper_cderr = p1 chamfer * xyz_unit
    }
}

// ------------------------------------------------------------------
extern "C" void kernel_launch(void* const* d_in, const int* in_sizes, int n_in,
                              void* d_out, int out_size, void* d_ws, size_t ws_size,
                              hipStream_t stream) {
    const float* pred = (const float*)d_in[0];
    const float* gt   = (const float*)d_in[1];
    float* out = (float*)d_out;

    char* ws = (char*)d_ws;
    float4*   tgt4  = (float4*)ws;                                   // 2*B*NPTS float4 = 2 MB
    unsigned* minsq = (unsigned*)(ws + 2 * B_ * NPTS * sizeof(float4)); // 512 KB
    float*    sums  = (float*)(ws + 2 * B_ * NPTS * (sizeof(float4) + sizeof(unsigned)));

    prep_kernel<<<dim3(2 * B_ * NPTS / 256), 256, 0, stream>>>(pred, gt, tgt4, minsq);
    chamfer_pass<<<dim3(NCHUNK * NJT, B_, 2), BLK, 0, stream>>>(pred, gt, tgt4, minsq);
    reduce1_kernel<<<dim3(2 * B_), 256, 0, stream>>>(minsq, sums);
    reduce2_kernel<<<dim3(1), 64, 0, stream>>>(sums, out);
}

// Round 2
// 102.556 us; speedup vs baseline: 1.1607x; 1.1607x over previous
//
#include <hip/hip_runtime.h>

#define B_ 16
#define NPTS 4096            // points per batch (N == M == 4096)

constexpr int JT     = 512;            // target-tile size (LDS: 8 KB of float4)
constexpr int PPT    = 4;              // query points per thread (registers)
constexpr int BLK    = 256;            // threads per block
constexpr int CHUNK  = BLK * PPT;      // 1024 query points per block
constexpr int NCHUNK = NPTS / CHUNK;   // 4
constexpr int NJT    = NPTS / JT;      // 8

// ------------------------------------------------------------------
// main pass: block = (query chunk cx, target tile jt, batch b, dir).
// Stages JT targets into LDS as {-2x,-2y,-2z,|g|^2} (prescale folds the
// -2 so the inner body is 3 fma + 1 min per pair). Each thread keeps 4
// query points in registers, writes its tile-min of clamped d^2 to a
// per-(jt) partial slot -- no atomics, no init required.
__global__ __launch_bounds__(BLK) void chamfer_pass(
        const float* __restrict__ pred, const float* __restrict__ gt,
        float* __restrict__ partial) {
    const int cx  = blockIdx.x & (NCHUNK - 1);   // query chunk
    const int jt  = blockIdx.x >> 2;             // target tile
    const int b   = blockIdx.y;
    const int dir = blockIdx.z;

    const float* qsrc = dir ? gt   : pred;       // queries
    const float* tsrc = dir ? pred : gt;         // targets

    __shared__ float4 sh[JT];
    {
        const float* tp = tsrc + (b * NPTS + jt * JT) * 3;
        for (int k = threadIdx.x; k < JT; k += BLK) {
            float x = tp[k * 3 + 0];
            float y = tp[k * 3 + 1];
            float z = tp[k * 3 + 2];
            sh[k] = make_float4(-2.0f * x, -2.0f * y, -2.0f * z,
                                fmaf(x, x, fmaf(y, y, z * z)));
        }
    }

    float px[PPT], py[PPT], pz[PPT], mn[PPT];
    const int qbase = b * NPTS + cx * CHUNK + threadIdx.x;
#pragma unroll
    for (int q = 0; q < PPT; q++) {
        int idx = qbase + q * BLK;
        px[q] = qsrc[idx * 3 + 0];
        py[q] = qsrc[idx * 3 + 1];
        pz[q] = qsrc[idx * 3 + 2];
        mn[q] = 1e30f;
    }
    __syncthreads();

#pragma unroll 8
    for (int j = 0; j < JT; j++) {
        float4 g = sh[j];   // uniform address -> broadcast ds_read_b128
#pragma unroll
        for (int q = 0; q < PPT; q++) {
            float t = fmaf(g.x, px[q], g.w);     // |g|^2 - 2 q.g  (3-fma chain)
            t = fmaf(g.y, py[q], t);
            t = fmaf(g.z, pz[q], t);
            mn[q] = fminf(mn[q], t);
        }
    }

    // partial[dir][b][jt][point] = clamped min d^2 over this tile
    float* slot = partial + ((dir * B_ + b) * NJT + jt) * NPTS + cx * CHUNK;
#pragma unroll
    for (int q = 0; q < PPT; q++) {
        float x2 = fmaf(px[q], px[q], fmaf(py[q], py[q], pz[q] * pz[q]));
        slot[q * BLK + threadIdx.x] = fmaxf(mn[q] + x2, 0.0f);
    }
}

// ------------------------------------------------------------------
// reduce1: one block per (dir,b); min over NJT slots, sqrt, sum 4096 pts.
__global__ void reduce1_kernel(const float* __restrict__ partial,
                               float* __restrict__ sums) {
    const float* p = partial + blockIdx.x * (NJT * NPTS);
    float s = 0.0f;
    for (int k = threadIdx.x; k < NPTS; k += 256) {
        float v = p[k];
#pragma unroll
        for (int jt = 1; jt < NJT; jt++)
            v = fminf(v, p[jt * NPTS + k]);
        s += sqrtf(v);
    }
    for (int off = 32; off; off >>= 1) s += __shfl_down(s, off);
    __shared__ float ps[4];
    if ((threadIdx.x & 63) == 0) ps[threadIdx.x >> 6] = s;
    __syncthreads();
    if (threadIdx.x == 0)
        sums[blockIdx.x] = ps[0] + ps[1] + ps[2] + ps[3];
}

// ------------------------------------------------------------------
// reduce2: combine 32 partial sums -> loss; write the 3 outputs.
__global__ void reduce2_kernel(const float* __restrict__ sums,
                               float* __restrict__ out) {
    float s = (threadIdx.x < 32) ? sums[threadIdx.x] : 0.0f;
    for (int off = 32; off; off >>= 1) s += __shfl_down(s, off);
    if (threadIdx.x == 0) {
        float loss = s * (1.0f / (float)(B_ * NPTS));
        out[0] = loss;          // WEIGHT * loss, WEIGHT = 1
        out[1] = loss;          // helper_loss
        out[2] = 0.1f * loss;   // helper_cderr = p1 chamfer * xyz_unit
    }
}

// ------------------------------------------------------------------
extern "C" void kernel_launch(void* const* d_in, const int* in_sizes, int n_in,
                              void* d_out, int out_size, void* d_ws, size_t ws_size,
                              hipStream_t stream) {
    const float* pred = (const float*)d_in[0];
    const float* gt   = (const float*)d_in[1];
    float* out = (float*)d_out;

    char* ws = (char*)d_ws;
    float* partial = (float*)ws;                               // 2*B*NJT*NPTS floats = 4 MB
    float* sums    = (float*)(ws + 2 * B_ * NJT * NPTS * sizeof(float));

    chamfer_pass<<<dim3(NCHUNK * NJT, B_, 2), BLK, 0, stream>>>(pred, gt, partial);
    reduce1_kernel<<<dim3(2 * B_), 256, 0, stream>>>(partial, sums);
    reduce2_kernel<<<dim3(1), 64, 0, stream>>>(sums, out);
}